// Round 1
// 2788.901 us; speedup vs baseline: 1.1092x; 1.1092x over previous
//
#include <hip/hip_runtime.h>
#include <hip/hip_bf16.h>
#include <math.h>

// Problem constants
#define Bn 64
#define Tn 512
#define In 256
#define Hn 1024
#define Fn 11
#define TP1 513       // T+1 slots in r history (slot 0 = h0)

typedef __attribute__((ext_vector_type(8))) short short8;  // 8 bf16 (4 VGPRs)
typedef __attribute__((ext_vector_type(4))) float f32x4;
typedef unsigned short u16;
typedef unsigned int u32;
typedef unsigned long long u64;
typedef __hip_bfloat16 bf16;

__device__ __forceinline__ float sigm(float x) { return 1.0f / (1.0f + __expf(-x)); }
// fast tanh via hardware exp; clamped so e never overflows (tanh(+-15) == +-1 in f32)
__device__ __forceinline__ float ftanh(float x) {
  float xc = fminf(fmaxf(x, -15.0f), 15.0f);
  float e = __expf(2.0f * xc);
  return (e - 1.0f) / (e + 1.0f);
}
__device__ __forceinline__ short8 ld8(const bf16* p) { return *(const short8*)p; }

// ---------------- cast inputs to bf16, zero barrier flags ----------------
__global__ void k_cast(const float* __restrict__ x, const float* __restrict__ whh,
                       const float* __restrict__ wih, const float* __restrict__ h0,
                       bf16* __restrict__ xb, bf16* __restrict__ whhb,
                       bf16* __restrict__ wihb, bf16* __restrict__ rb,
                       u32* __restrict__ bar)
{
  long i = (long)blockIdx.x * 256 + threadIdx.x;
  if (i < 8388608L) {                                   // x: B*T*I
    xb[i] = __float2bfloat16(x[i]);
  } else if (i < 8388608L + 4194304L) {                 // W_hh: 4H*H
    long j = i - 8388608L; whhb[j] = __float2bfloat16(whh[j]);
  } else if (i < 8388608L + 4194304L + 1048576L) {      // W_ih: 4H*I
    long j = i - 8388608L - 4194304L; wihb[j] = __float2bfloat16(wih[j]);
  } else if (i < 8388608L + 4194304L + 1048576L + 65536L) {  // h0 -> r slot 0
    long j = i - 8388608L - 4194304L - 1048576L;
    int b = (int)(j >> 10), h = (int)(j & 1023);
    rb[((long)b * TP1) * Hn + h] = __float2bfloat16(h0[j]);
  }
  if (blockIdx.x == 0 && threadIdx.x < 256) bar[threadIdx.x] = 0u;  // 4 groups x 64 flags
}

// ---------------- fold post-LSTM linears: G[16][H] = V @ W_sh ----------------
// rows 0..10: W_state, 11: W_reward, 12: w_att_s, 13: w_att_r, 14/15: zero
__global__ void k_fold_part(const float* __restrict__ Wsh, const float* __restrict__ Wst,
                            const float* __restrict__ Wrw, const float* __restrict__ was,
                            const float* __restrict__ war, float* __restrict__ Gpart)
{
  int k = blockIdx.x * 256 + threadIdx.x;   // grid.x = 4 -> k in [0,1024)
  int j = blockIdx.y;                       // 16
  int h0 = blockIdx.z * 128;                // grid.z = 8
  const float* V = nullptr;
  if (j < 11) V = Wst + j * Hn;
  else if (j == 11) V = Wrw;
  else if (j == 12) V = was;
  else if (j == 13) V = war;
  float acc = 0.f;
  if (V) {
    for (int h = h0; h < h0 + 128; ++h) acc += V[h] * Wsh[(long)h * Hn + k];
  }
  Gpart[((long)blockIdx.z * 16 + j) * Hn + k] = acc;
}

__global__ void k_g2b(const float* __restrict__ Gpart, bf16* __restrict__ Gb)
{
  int i = blockIdx.x * 256 + threadIdx.x;   // 16384
  float s = 0.f;
  for (int z = 0; z < 8; ++z) s += Gpart[(long)z * 16384 + i];
  Gb[i] = __float2bfloat16(s);
}

// constants folded through the attention average (weights sum to 1)
__global__ void k_const(const float* __restrict__ bsh, const float* __restrict__ Wst,
                        const float* __restrict__ bst, const float* __restrict__ Wrw,
                        const float* __restrict__ brw, const float* __restrict__ was,
                        const float* __restrict__ bas, const float* __restrict__ war,
                        const float* __restrict__ bar_, float* __restrict__ cv)
{
  int j = threadIdx.x;
  if (j >= 16) return;
  const float* V = nullptr; float bb = 0.f;
  if (j < 11) { V = Wst + j * Hn; bb = bst[j]; }
  else if (j == 11) { V = Wrw; bb = brw[0]; }
  else if (j == 12) { V = was; bb = bas[0]; }
  else if (j == 13) { V = war; bb = bar_[0]; }
  float acc = 0.f;
  if (V) for (int h = 0; h < Hn; ++h) acc += bsh[h] * V[h];
  cv[j] = acc + bb;
}

// ---------------- the sequential LSTM, persistent cooperative kernel ----------------
// 4 batch-groups x 64 WGs. WG owns 16 h-dims (64 z-rows). Waves split K 4-way
// (10 kb-blocks each); all cross-WG traffic is relaxed agent-scope (sc0 sc1,
// served at Infinity Cache) -> NO buffer_inv / buffer_wbl2 cache maintenance.
// Poll discipline: ONLY wave 0 spins on the 64 flags (4x fewer waves hammering
// the flag cache lines at IF); waves 1-3 park at a barrier until release.
__global__ void __launch_bounds__(256, 1)
k_lstm(const bf16* __restrict__ xb, const bf16* __restrict__ whhb,
       const bf16* __restrict__ wihb, const float* __restrict__ bih,
       const float* __restrict__ bhh, const float* __restrict__ c0,
       bf16* __restrict__ rb, float* __restrict__ outH, float* __restrict__ outC,
       u32* flags)
{
  const int tid = threadIdx.x;
  const int w = tid >> 6, l = tid & 63;
  const int lo16 = l & 15, q = l >> 4;
  const int g = blockIdx.x >> 6;       // batch group 0..3 (16 batches each)
  const int mem = blockIdx.x & 63;     // member in group
  const int bG0 = g << 4;

  // B-fragments in registers: wave w covers kb in [w*10, w*10+10); n-tile j = gate j.
  // B row for (gate j, lane lo16) = j*H + mem*16 + lo16.
  short8 wf[4][10];
  {
    const int wrow = (mem << 4) + lo16;
#pragma unroll
    for (int j = 0; j < 4; ++j) {
#pragma unroll
      for (int kk = 0; kk < 10; ++kk) {
        const int kb = w * 10 + kk;
        if (kb < 32)
          wf[j][kk] = ld8(whhb + (long)(j * Hn + wrow) * Hn + kb * 32 + q * 8);
        else
          wf[j][kk] = ld8(wihb + (long)(j * Hn + wrow) * In + (kb - 32) * 32 + q * 8);
      }
    }
  }

  // gate-phase mapping: thread -> (batch bl, local dim diml)
  const int bl = tid & 15, diml = tid >> 4;
  const int bb = bG0 + bl;
  const int dloc = (mem << 4) + diml;
  const float bi0 = bih[dloc]          + bhh[dloc];
  const float bi1 = bih[Hn + dloc]     + bhh[Hn + dloc];
  const float bi2 = bih[2 * Hn + dloc] + bhh[2 * Hn + dloc];
  const float bi3 = bih[3 * Hn + dloc] + bhh[3 * Hn + dloc];
  float cst = c0[(long)bb * Hn + dloc];

  // staging mapping: 16 threads per batch row
  const int sb = tid >> 4, tl = tid & 15;

  // LDS: A-tile 16 rows x (1280 dims *2B + 16B pad) + partial-z buffer
  __shared__ __align__(16) unsigned char Atile[16 * 2576];
  __shared__ float zbuf[4][4][16][17];   // [K-quarter][gate][diml][batch+pad]

  u32* fl = flags + g * 64;

  const u64* xrow = (const u64*)(xb + (long)(bG0 + sb) * Tn * In);
  const u64* rrow = (const u64*)(rb + (long)(bG0 + sb) * TP1 * Hn);
  u64* ldsr = (u64*)(Atile + sb * 2576);
  u64* ldsx = (u64*)(Atile + sb * 2576 + 2048);

  for (int t = 0; t < Tn; ++t) {
    // x prefetch (normal cached loads; independent of the recurrence)
    u64 xv[4];
    {
      const u64* xp = xrow + (long)t * (In / 4);
#pragma unroll
      for (int jx = 0; jx < 4; ++jx) xv[jx] = xp[tl + 16 * jx];
    }

    // wait for step t-1's h: wave 0 alone polls the 64 flags (relaxed agent
    // loads, no fences); other waves sleep at the barrier -> 4x less IF
    // contention on the flag lines. Own flag (l==mem) was already set by this
    // WG at the end of step t-1, so no exclusion needed.
    if (t > 0) {
      if (w == 0) {
        const u32 tgt = (u32)t;
        while (true) {
          u32 f = __hip_atomic_load(&fl[l], __ATOMIC_RELAXED, __HIP_MEMORY_SCOPE_AGENT);
          if (__ballot(f < tgt) == 0ULL) break;
        }
        __asm__ __volatile__("" ::: "memory");
      }
      __syncthreads();   // release waves 1-3; their IF loads issue after this
    }

    // r staging: sc0 sc1 loads straight from IF (bypass non-coherent L1/L2)
    u64 rv[16];
    {
      const u64* rp = rrow + (long)t * (Hn / 4);
#pragma unroll
      for (int j = 0; j < 16; ++j)
        rv[j] = __hip_atomic_load(rp + tl + 16 * j, __ATOMIC_RELAXED, __HIP_MEMORY_SCOPE_AGENT);
    }
#pragma unroll
    for (int jx = 0; jx < 4; ++jx) ldsx[tl + 16 * jx] = xv[jx];
#pragma unroll
    for (int j = 0; j < 16; ++j) ldsr[tl + 16 * j] = rv[j];
    __syncthreads();

    // MFMA: wave w's K-quarter. Prefetch ALL 10 A-frags into registers first
    // (removes repeated LDS latency from the dependent accumulate chain; we
    // run 1 WG/CU so VGPR headroom is ample), then the 40-MFMA burst.
    f32x4 a0 = {0,0,0,0}, a1 = {0,0,0,0}, a2 = {0,0,0,0}, a3 = {0,0,0,0};
    short8 af[10];
#pragma unroll
    for (int kk = 0; kk < 10; ++kk)
      af[kk] = *(const short8*)(Atile + lo16 * 2576 + ((w * 10 + kk) * 32 + q * 8) * 2);
#pragma unroll
    for (int kk = 0; kk < 10; ++kk) {
      a0 = __builtin_amdgcn_mfma_f32_16x16x32_bf16(af[kk], wf[0][kk], a0, 0, 0, 0);
      a1 = __builtin_amdgcn_mfma_f32_16x16x32_bf16(af[kk], wf[1][kk], a1, 0, 0, 0);
      a2 = __builtin_amdgcn_mfma_f32_16x16x32_bf16(af[kk], wf[2][kk], a2, 0, 0, 0);
      a3 = __builtin_amdgcn_mfma_f32_16x16x32_bf16(af[kk], wf[3][kk], a3, 0, 0, 0);
    }
    // D layout: m(batch) = q*4+reg, n(diml) = lo16
#pragma unroll
    for (int r = 0; r < 4; ++r) {
      zbuf[w][0][lo16][q * 4 + r] = a0[r];
      zbuf[w][1][lo16][q * 4 + r] = a1[r];
      zbuf[w][2][lo16][q * 4 + r] = a2[r];
      zbuf[w][3][lo16][q * 4 + r] = a3[r];
    }
    __syncthreads();

    // gates: sum the 4 K-partials
    float zi = zbuf[0][0][diml][bl] + zbuf[1][0][diml][bl] + zbuf[2][0][diml][bl] + zbuf[3][0][diml][bl] + bi0;
    float zf = zbuf[0][1][diml][bl] + zbuf[1][1][diml][bl] + zbuf[2][1][diml][bl] + zbuf[3][1][diml][bl] + bi1;
    float zg = zbuf[0][2][diml][bl] + zbuf[1][2][diml][bl] + zbuf[2][2][diml][bl] + zbuf[3][2][diml][bl] + bi2;
    float zo = zbuf[0][3][diml][bl] + zbuf[1][3][diml][bl] + zbuf[2][3][diml][bl] + zbuf[3][3][diml][bl] + bi3;
    float iv = sigm(zi), fv = sigm(zf), gv = ftanh(zg), ov = sigm(zo);
    cst = fv * cst + iv * gv;
    float hv = ov * ftanh(cst);

    // packed u32 h store, relaxed agent (sc0 sc1 -> IF, no L2 dirty lines)
    float ph = __shfl_xor(hv, 16, 64);          // partner has diml^1
    u16 mb = __builtin_bit_cast(u16, __float2bfloat16(hv));
    u16 pb = __builtin_bit_cast(u16, __float2bfloat16(ph));
    if ((diml & 1) == 0) {
      u32 pack = (u32)mb | ((u32)pb << 16);
      u32* dst = (u32*)(rb + ((long)bb * TP1 + t + 1) * Hn + dloc);
      __hip_atomic_store(dst, pack, __ATOMIC_RELAXED, __HIP_MEMORY_SCOPE_AGENT);
    }
    if (t == Tn - 1) {
      outH[(long)bb * Hn + dloc] = hv;
      outC[(long)bb * Hn + dloc] = cst;
    }

    // drain this wave's stores to their coherence point, then block barrier
    __asm__ __volatile__("s_waitcnt vmcnt(0)" ::: "memory");
    __syncthreads();
    if (tid == 0 && t < Tn - 1)
      __hip_atomic_store(&fl[mem], (u32)(t + 1), __ATOMIC_RELAXED, __HIP_MEMORY_SCOPE_AGENT);
  }
}

// ---------------- project r onto folded 16-dim basis: P[B*T][16] ----------------
__global__ void k_proj(const bf16* __restrict__ rb, const bf16* __restrict__ Gb,
                       const float* __restrict__ cv, float* __restrict__ P)
{
  const int tid = threadIdx.x;
  const int w = tid >> 6, l = tid & 63;
  const int lo16 = l & 15, q = l >> 4;
  const int row = blockIdx.x * 64 + w * 16 + lo16;    // (b,t) flat
  const int b = row >> 9, t = row & 511;
  const bf16* ap = rb + ((long)b * TP1 + t + 1) * Hn + q * 8;
  const bf16* gp = Gb + (long)lo16 * Hn + q * 8;
  f32x4 a0 = {0,0,0,0}, a1 = {0,0,0,0};
#pragma unroll
  for (int kb = 0; kb < 32; kb += 2) {
    a0 = __builtin_amdgcn_mfma_f32_16x16x32_bf16(ld8(ap + kb * 32),      ld8(gp + kb * 32),      a0, 0, 0, 0);
    a1 = __builtin_amdgcn_mfma_f32_16x16x32_bf16(ld8(ap + kb * 32 + 32), ld8(gp + kb * 32 + 32), a1, 0, 0, 0);
  }
  f32x4 z = a0 + a1;
  float c = cv[lo16];
  const int rowbase = blockIdx.x * 64 + w * 16;
#pragma unroll
  for (int r = 0; r < 4; ++r)
    P[(long)(rowbase + q * 4 + r) * 16 + lo16] = z[r] + c;
}

// ---------------- per-batch online-softmax prefix scan ----------------
__global__ void k_scan(const float* __restrict__ P, float* __restrict__ outS,
                       float* __restrict__ outR)
{
  __shared__ float sp[Tn * 16];
  const int b = blockIdx.x, tid = threadIdx.x;
  for (int i = tid; i < Tn * 16; i += 64) sp[i] = P[(long)b * Tn * 16 + i];
  __syncthreads();
  const int j = tid;
  if (j < 12) {
    const bool isR = (j == 11);
    float m = -INFINITY, den = 0.f, num = 0.f;
    for (int t = 0; t < Tn; ++t) {
      float val = sp[t * 16 + j];
      float ll = sp[t * 16 + (isR ? 13 : 12)];
      float mn = fmaxf(m, ll);
      float al = __expf(m - mn);
      float e  = __expf(ll - mn);
      den = den * al + e;
      num = num * al + e * val;
      m = mn;
      float o = num / den;
      if (isR) outR[(long)b * Tn + t] = o;
      else     outS[(long)(b * Tn + t) * Fn + j] = o;
    }
  }
}

extern "C" void kernel_launch(void* const* d_in, const int* in_sizes, int n_in,
                              void* d_out, int out_size, void* d_ws, size_t ws_size,
                              hipStream_t stream)
{
  (void)in_sizes; (void)n_in; (void)out_size; (void)ws_size;
  const float* x    = (const float*)d_in[0];
  const float* h0   = (const float*)d_in[2];
  const float* c0   = (const float*)d_in[3];
  const float* Wih  = (const float*)d_in[4];
  const float* Whh  = (const float*)d_in[5];
  const float* bih  = (const float*)d_in[6];
  const float* bhh  = (const float*)d_in[7];
  const float* Wsh  = (const float*)d_in[8];
  const float* bsh  = (const float*)d_in[9];
  const float* was  = (const float*)d_in[10];
  const float* bas  = (const float*)d_in[11];
  const float* war  = (const float*)d_in[12];
  const float* barr = (const float*)d_in[13];
  const float* Wst  = (const float*)d_in[14];
  const float* bst  = (const float*)d_in[15];
  const float* Wrw  = (const float*)d_in[16];
  const float* brw  = (const float*)d_in[17];

  char* ws = (char*)d_ws;
  size_t off = 0;
  auto alloc = [&](size_t bytes) -> void* {
    void* p = ws + off; off += (bytes + 255) & ~(size_t)255; return p;
  };
  bf16* xb    = (bf16*)alloc((size_t)Bn * Tn * In * 2);
  bf16* whhb  = (bf16*)alloc((size_t)4 * Hn * Hn * 2);
  bf16* wihb  = (bf16*)alloc((size_t)4 * Hn * In * 2);
  bf16* rb    = (bf16*)alloc((size_t)Bn * TP1 * Hn * 2);
  bf16* Gb    = (bf16*)alloc((size_t)16 * Hn * 2);
  float* Gpart= (float*)alloc((size_t)8 * 16 * Hn * 4);
  float* cv   = (float*)alloc(16 * 4);
  float* P    = (float*)alloc((size_t)Bn * Tn * 16 * 4);
  u32*  barp  = (u32*)alloc(1024);

  float* outS = (float*)d_out;
  float* outR = outS + (size_t)Bn * Tn * Fn;
  float* outH = outR + (size_t)Bn * Tn;
  float* outC = outH + (size_t)Bn * Hn;

  const long NCAST = 8388608L + 4194304L + 1048576L + 65536L;
  k_cast<<<dim3((unsigned)(NCAST / 256)), 256, 0, stream>>>(x, Whh, Wih, h0, xb, whhb, wihb, rb, barp);
  k_fold_part<<<dim3(4, 16, 8), 256, 0, stream>>>(Wsh, Wst, Wrw, was, war, Gpart);
  k_g2b<<<64, 256, 0, stream>>>(Gpart, Gb);
  k_const<<<1, 64, 0, stream>>>(bsh, Wst, bst, Wrw, brw, was, bas, war, barr, cv);

  {
    void* args[] = { (void*)&xb, (void*)&whhb, (void*)&wihb, (void*)&bih, (void*)&bhh,
                     (void*)&c0, (void*)&rb, (void*)&outH, (void*)&outC, (void*)&barp };
    hipError_t e = hipLaunchCooperativeKernel((const void*)k_lstm, dim3(256), dim3(256),
                                              args, 0, stream);
    if (e != hipSuccess) {
      // fallback: plain launch (barrier is hand-rolled; 256 blocks at 1/CU co-reside)
      k_lstm<<<256, 256, 0, stream>>>(xb, whhb, wihb, bih, bhh, c0, rb, outH, outC, barp);
    }
  }

  k_proj<<<512, 256, 0, stream>>>(rb, Gb, cv, P);
  k_scan<<<64, 64, 0, stream>>>(P, outS, outR);
}

// Round 2
// 2780.783 us; speedup vs baseline: 1.1124x; 1.0029x over previous
//
#include <hip/hip_runtime.h>
#include <hip/hip_bf16.h>
#include <math.h>

// Problem constants
#define Bn 64
#define Tn 512
#define In 256
#define Hn 1024
#define Fn 11
#define TP1 513       // T+1 slots in r history (slot 0 = h0)

typedef __attribute__((ext_vector_type(8))) short short8;  // 8 bf16 (4 VGPRs)
typedef __attribute__((ext_vector_type(4))) float f32x4;
typedef unsigned short u16;
typedef unsigned int u32;
typedef unsigned long long u64;
typedef __hip_bfloat16 bf16;

__device__ __forceinline__ float sigm(float x) { return 1.0f / (1.0f + __expf(-x)); }
// fast tanh via hardware exp; clamped so e never overflows (tanh(+-15) == +-1 in f32)
__device__ __forceinline__ float ftanh(float x) {
  float xc = fminf(fmaxf(x, -15.0f), 15.0f);
  float e = __expf(2.0f * xc);
  return (e - 1.0f) / (e + 1.0f);
}
__device__ __forceinline__ short8 ld8(const bf16* p) { return *(const short8*)p; }

// ================= common small kernels (both paths) =================

// fold post-LSTM linears: G[16][H] = V @ W_sh
// rows 0..10: W_state, 11: W_reward, 12: w_att_s, 13: w_att_r, 14/15: zero
__global__ void k_fold_part(const float* __restrict__ Wsh, const float* __restrict__ Wst,
                            const float* __restrict__ Wrw, const float* __restrict__ was,
                            const float* __restrict__ war, float* __restrict__ Gpart)
{
  int k = blockIdx.x * 256 + threadIdx.x;   // grid.x = 4 -> k in [0,1024)
  int j = blockIdx.y;                       // 16
  int h0 = blockIdx.z * 128;                // grid.z = 8
  const float* V = nullptr;
  if (j < 11) V = Wst + j * Hn;
  else if (j == 11) V = Wrw;
  else if (j == 12) V = was;
  else if (j == 13) V = war;
  float acc = 0.f;
  if (V) {
    for (int h = h0; h < h0 + 128; ++h) acc += V[h] * Wsh[(long)h * Hn + k];
  }
  Gpart[((long)blockIdx.z * 16 + j) * Hn + k] = acc;
}

__global__ void k_g2b(const float* __restrict__ Gpart, bf16* __restrict__ Gb)
{
  int i = blockIdx.x * 256 + threadIdx.x;   // 16384
  float s = 0.f;
  for (int z = 0; z < 8; ++z) s += Gpart[(long)z * 16384 + i];
  Gb[i] = __float2bfloat16(s);
}

__global__ void k_const(const float* __restrict__ bsh, const float* __restrict__ Wst,
                        const float* __restrict__ bst, const float* __restrict__ Wrw,
                        const float* __restrict__ brw, const float* __restrict__ was,
                        const float* __restrict__ bas, const float* __restrict__ war,
                        const float* __restrict__ bar_, float* __restrict__ cv)
{
  int j = threadIdx.x;
  if (j >= 16) return;
  const float* V = nullptr; float bb = 0.f;
  if (j < 11) { V = Wst + j * Hn; bb = bst[j]; }
  else if (j == 11) { V = Wrw; bb = brw[0]; }
  else if (j == 12) { V = was; bb = bas[0]; }
  else if (j == 13) { V = war; bb = bar_[0]; }
  float acc = 0.f;
  if (V) for (int h = 0; h < Hn; ++h) acc += bsh[h] * V[h];
  cv[j] = acc + bb;
}

// project r onto folded 16-dim basis: P[B*T][16]
__global__ void k_proj(const bf16* __restrict__ rb, const bf16* __restrict__ Gb,
                       const float* __restrict__ cv, float* __restrict__ P)
{
  const int tid = threadIdx.x;
  const int w = tid >> 6, l = tid & 63;
  const int lo16 = l & 15, q = l >> 4;
  const int row = blockIdx.x * 64 + w * 16 + lo16;    // (b,t) flat
  const int b = row >> 9, t = row & 511;
  const bf16* ap = rb + ((long)b * TP1 + t + 1) * Hn + q * 8;
  const bf16* gp = Gb + (long)lo16 * Hn + q * 8;
  f32x4 a0 = {0,0,0,0}, a1 = {0,0,0,0};
#pragma unroll
  for (int kb = 0; kb < 32; kb += 2) {
    a0 = __builtin_amdgcn_mfma_f32_16x16x32_bf16(ld8(ap + kb * 32),      ld8(gp + kb * 32),      a0, 0, 0, 0);
    a1 = __builtin_amdgcn_mfma_f32_16x16x32_bf16(ld8(ap + kb * 32 + 32), ld8(gp + kb * 32 + 32), a1, 0, 0, 0);
  }
  f32x4 z = a0 + a1;
  float c = cv[lo16];
  const int rowbase = blockIdx.x * 64 + w * 16;
#pragma unroll
  for (int r = 0; r < 4; ++r)
    P[(long)(rowbase + q * 4 + r) * 16 + lo16] = z[r] + c;
}

// per-batch online-softmax prefix scan
__global__ void k_scan(const float* __restrict__ P, float* __restrict__ outS,
                       float* __restrict__ outR)
{
  __shared__ float sp[Tn * 16];
  const int b = blockIdx.x, tid = threadIdx.x;
  for (int i = tid; i < Tn * 16; i += 64) sp[i] = P[(long)b * Tn * 16 + i];
  __syncthreads();
  const int j = tid;
  if (j < 12) {
    const bool isR = (j == 11);
    float m = -INFINITY, den = 0.f, num = 0.f;
    for (int t = 0; t < Tn; ++t) {
      float val = sp[t * 16 + j];
      float ll = sp[t * 16 + (isR ? 13 : 12)];
      float mn = fmaxf(m, ll);
      float al = __expf(m - mn);
      float e  = __expf(ll - mn);
      den = den * al + e;
      num = num * al + e * val;
      m = mn;
      float o = num / den;
      if (isR) outR[(long)b * Tn + t] = o;
      else     outS[(long)(b * Tn + t) * Fn + j] = o;
    }
  }
}

// ================= NEW fast path: XCD-local LSTM + hoisted W_ih GEMM =================

// cast weights + h0, zero flags (bar[0..256) = group flags, bar[256..264) = xcd counters)
__global__ void k_castw(const float* __restrict__ whh, const float* __restrict__ wih,
                        const float* __restrict__ h0, bf16* __restrict__ whhb,
                        bf16* __restrict__ wihb, bf16* __restrict__ rb,
                        u32* __restrict__ bar)
{
  long i = (long)blockIdx.x * 256 + threadIdx.x;
  if (i < 4194304L) {
    whhb[i] = __float2bfloat16(whh[i]);
  } else if (i < 4194304L + 1048576L) {
    long j = i - 4194304L; wihb[j] = __float2bfloat16(wih[j]);
  } else if (i < 4194304L + 1048576L + 65536L) {
    long j = i - 4194304L - 1048576L;
    int b = (int)(j >> 10), h = (int)(j & 1023);
    rb[((long)b * TP1) * Hn + h] = __float2bfloat16(h0[j]);
  }
  if (blockIdx.x == 0 && threadIdx.x < 256) bar[threadIdx.x] = 0u;
  if (blockIdx.x == 1 && threadIdx.x < 256) bar[256 + threadIdx.x] = 0u;
}

// xz[t][b][d][jgate] (bf16) = x[b,t,:] @ W_ih[jgate*H+d, :]   -- no recurrence, big GEMM
// grid: (16 n-blocks, 2048 m-tiles); WG = 256 thr, 4 waves; wave: 16m x 64n, K=256
__global__ void k_xz(const float* __restrict__ x, const bf16* __restrict__ wihb,
                     bf16* __restrict__ xz)
{
  const int tid = threadIdx.x;
  const int w = tid >> 6, l = tid & 63;
  const int lo16 = l & 15, q = l >> 4;
  const int mt = blockIdx.y;           // 0..2047
  const int b = mt >> 5;               // 32 m-tiles per batch
  const int t0 = (mt & 31) << 4;
  const int n0 = blockIdx.x * 256 + w * 64;
  short8 afr[8];
  const float* xr = x + ((long)b * Tn + t0 + lo16) * In + q * 8;
#pragma unroll
  for (int kb = 0; kb < 8; ++kb) {
    short8 s;
#pragma unroll
    for (int e = 0; e < 8; ++e)
      s[e] = __builtin_bit_cast(u16, __float2bfloat16(xr[kb * 32 + e]));
    afr[kb] = s;
  }
  f32x4 ac[4] = {{0,0,0,0},{0,0,0,0},{0,0,0,0},{0,0,0,0}};
#pragma unroll
  for (int nt = 0; nt < 4; ++nt) {
    const bf16* wr = wihb + (long)(n0 + nt * 16 + lo16) * In + q * 8;
#pragma unroll
    for (int kb = 0; kb < 8; ++kb)
      ac[nt] = __builtin_amdgcn_mfma_f32_16x16x32_bf16(afr[kb], ld8(wr + kb * 32), ac[nt], 0, 0, 0);
  }
#pragma unroll
  for (int nt = 0; nt < 4; ++nt) {
    const int n = n0 + nt * 16 + lo16;
    const int j = n >> 10, d = n & 1023;
#pragma unroll
    for (int r = 0; r < 4; ++r) {
      const int t = t0 + q * 4 + r;
      xz[(((long)t * Bn + b) * Hn + d) * 4 + j] = __float2bfloat16(ac[nt][r]);
    }
  }
}

// The sequential LSTM: 8 groups x 32 WGs, ONE GROUP PER PHYSICAL XCD.
// Group = actual HW_REG_XCC_ID; rank via per-XCD atomic counter (mapping-independent).
// All cross-WG traffic (h, flags) stays in the XCD's L2: stores/loads with sc0
// (L1-bypass, L2-coherent) -> ~200cy round trips instead of ~900cy at IF.
// 512 thr (8 waves); wave (kq=w&1, nh=w>>1): K-half kq, ntiles {nh*2, nh*2+1}.
// VGPR > 128 per wave forces exactly 1 WG/CU -> exactly 32 WGs per XCD.
__global__ void __launch_bounds__(512, 2)
k_lstm_x(const bf16* __restrict__ whhb, const float* __restrict__ bih,
         const float* __restrict__ bhh, const float* __restrict__ c0,
         const bf16* __restrict__ xz, bf16* __restrict__ rb,
         float* __restrict__ outH, float* __restrict__ outC, u32* flags)
{
  const int tid = threadIdx.x;
  const int w = tid >> 6, l = tid & 63;
  const int lo16 = l & 15, q = l >> 4;
  const int kq = w & 1, nh = w >> 1;

  __shared__ int s_g, s_mem;
  __shared__ __align__(16) unsigned char Atile[16 * 2064];  // 16 rows x 1024 bf16 (+8B pad)
  __shared__ float zbuf[2][8][16][17];                       // [K-half][ntile][n][m+pad]

  u32* cnt = flags + 256;
  if (tid == 0) {
    u32 xcc;
    asm volatile("s_getreg_b32 %0, hwreg(HW_REG_XCC_ID)" : "=s"(xcc));
    u32 r = atomicAdd(&cnt[xcc & 7], 1u);
    s_g = (int)(xcc & 7);
    s_mem = (int)(r & 31);
  }
  __syncthreads();
  const int g = s_g, mem = s_mem;
  const int bG0 = g << 3;                    // 8 batches per group

  // zero A-tile rows 8..15 once (MFMA m-rows 8..15 must stay 0)
  {
    u64* za = (u64*)(Atile + 8 * 2064);
    for (int i = tid; i < (8 * 2064) / 8; i += 512) za[i] = 0;
  }

  // weight fragments (W_hh only; W_ih hoisted into xz): 32 x short8 = 128 VGPR
  short8 wf[2][16];
#pragma unroll
  for (int nt = 0; nt < 2; ++nt) {
    const int ntg = nh * 2 + nt;
    const int j = ntg >> 1;
    const long row = (long)(j * Hn + (mem << 5) + ((ntg & 1) << 4) + lo16);
#pragma unroll
    for (int kk = 0; kk < 16; ++kk)
      wf[nt][kk] = ld8(whhb + row * Hn + (kq * 16 + kk) * 32 + q * 8);
  }

  // gate-phase mapping (tid < 256): batch bl, local dim dl
  const int bl = tid & 7, dl = tid >> 3;
  const int bb = bG0 + bl;
  const int dloc = (mem << 5) + dl;
  float bi0 = 0, bi1 = 0, bi2 = 0, bi3 = 0, cst = 0;
  if (tid < 256) {
    bi0 = bih[dloc]          + bhh[dloc];
    bi1 = bih[Hn + dloc]     + bhh[Hn + dloc];
    bi2 = bih[2 * Hn + dloc] + bhh[2 * Hn + dloc];
    bi3 = bih[3 * Hn + dloc] + bhh[3 * Hn + dloc];
    cst = c0[(long)bb * Hn + dloc];
  }

  u32* fl = flags + g * 32;                  // 32 flags = one 128B line per group
  const u64* xzq = (const u64*)xz;           // u64 idx = (t*64+bb)*1024 + dloc
  const u64* rbase = (const u64*)(rb + ((long)(bG0 + w) * TP1) * Hn) + l;
  u32* hbase = (u32*)(rb + ((long)bb * TP1 + 1) * Hn + dloc);

  for (int t = 0; t < Tn; ++t) {
    // xz prefetch: independent of recurrence, normal cached load, hides under poll
    u64 xzv = 0;
    if (tid < 256) xzv = xzq[((long)t * Bn + bb) * Hn + dloc];

    // wait for step t-1: wave 0 polls the group's 32 flags at L2 (sc0)
    if (t > 0) {
      if (w == 0) {
        const u32* fp = fl + (l & 31);
        const u32 tgt = (u32)t;
        while (true) {
          u32 f;
          asm volatile("global_load_dword %0, %1, off sc0\n\ts_waitcnt vmcnt(0)"
                       : "=v"(f) : "v"(fp) : "memory");
          if (__ballot(f < tgt) == 0ULL) break;
        }
      }
      __syncthreads();
    }

    // r staging: wave w loads batch bG0+w, slot t, sc0 (L1-bypass -> fresh L2 data)
    u64 rv0, rv1, rv2, rv3;
    {
      const u64* rp = rbase + (long)t * 256;
      asm volatile(
        "global_load_dwordx2 %0, %4, off sc0\n\t"
        "global_load_dwordx2 %1, %4, off offset:512 sc0\n\t"
        "global_load_dwordx2 %2, %4, off offset:1024 sc0\n\t"
        "global_load_dwordx2 %3, %4, off offset:1536 sc0\n\t"
        "s_waitcnt vmcnt(0)"
        : "=&v"(rv0), "=&v"(rv1), "=&v"(rv2), "=&v"(rv3)
        : "v"(rp) : "memory");
    }
    {
      u64* lr = (u64*)(Atile + w * 2064) + l;
      lr[0] = rv0; lr[64] = rv1; lr[128] = rv2; lr[192] = rv3;
    }
    __syncthreads();

    // MFMA: wave's K-half (16 kb) x 2 ntiles; A-frags prefetched in 2 batches of 8
    f32x4 a0 = {0,0,0,0}, a1 = {0,0,0,0};
    {
      const unsigned char* arow = Atile + lo16 * 2064 + kq * 1024 + q * 16;
      short8 af[8];
#pragma unroll
      for (int kk = 0; kk < 8; ++kk) af[kk] = *(const short8*)(arow + kk * 64);
#pragma unroll
      for (int kk = 0; kk < 8; ++kk) {
        a0 = __builtin_amdgcn_mfma_f32_16x16x32_bf16(af[kk], wf[0][kk], a0, 0, 0, 0);
        a1 = __builtin_amdgcn_mfma_f32_16x16x32_bf16(af[kk], wf[1][kk], a1, 0, 0, 0);
      }
#pragma unroll
      for (int kk = 0; kk < 8; ++kk) af[kk] = *(const short8*)(arow + 512 + kk * 64);
#pragma unroll
      for (int kk = 0; kk < 8; ++kk) {
        a0 = __builtin_amdgcn_mfma_f32_16x16x32_bf16(af[kk], wf[0][8 + kk], a0, 0, 0, 0);
        a1 = __builtin_amdgcn_mfma_f32_16x16x32_bf16(af[kk], wf[1][8 + kk], a1, 0, 0, 0);
      }
    }
    {
      const int ntg0 = nh * 2;
#pragma unroll
      for (int r = 0; r < 4; ++r) {
        zbuf[kq][ntg0][lo16][q * 4 + r]     = a0[r];
        zbuf[kq][ntg0 + 1][lo16][q * 4 + r] = a1[r];
      }
    }
    __syncthreads();

    if (tid < 256) {
      const int n16 = dl & 15, hi = dl >> 4;
      float z0 = zbuf[0][0 + hi][n16][bl] + zbuf[1][0 + hi][n16][bl];
      float z1 = zbuf[0][2 + hi][n16][bl] + zbuf[1][2 + hi][n16][bl];
      float z2 = zbuf[0][4 + hi][n16][bl] + zbuf[1][4 + hi][n16][bl];
      float z3 = zbuf[0][6 + hi][n16][bl] + zbuf[1][6 + hi][n16][bl];
      float x0 = __builtin_bit_cast(float, (u32)(u16)(xzv)       << 16);
      float x1 = __builtin_bit_cast(float, (u32)(u16)(xzv >> 16) << 16);
      float x2 = __builtin_bit_cast(float, (u32)(u16)(xzv >> 32) << 16);
      float x3 = __builtin_bit_cast(float, (u32)(u16)(xzv >> 48) << 16);
      float iv = sigm(z0 + x0 + bi0);
      float fv = sigm(z1 + x1 + bi1);
      float gv = ftanh(z2 + x2 + bi2);
      float ov = sigm(z3 + x3 + bi3);
      cst = fv * cst + iv * gv;
      float hv = ov * ftanh(cst);

      float ph = __shfl_xor(hv, 8, 64);       // partner holds dl^1
      if ((dl & 1) == 0) {
        u16 mb = __builtin_bit_cast(u16, __float2bfloat16(hv));
        u16 pb = __builtin_bit_cast(u16, __float2bfloat16(ph));
        u32 pack = (u32)mb | ((u32)pb << 16);
        u32* dst = hbase + (long)t * 512;
        asm volatile("global_store_dword %0, %1, off sc0" :: "v"(dst), "v"(pack) : "memory");
      }
      if (t == Tn - 1) {
        outH[(long)bb * Hn + dloc] = hv;
        outC[(long)bb * Hn + dloc] = cst;
      }
    }
    // drain h stores into L2, then signal
    asm volatile("s_waitcnt vmcnt(0)" ::: "memory");
    __syncthreads();
    if (tid == 0 && t < Tn - 1)
      asm volatile("global_store_dword %0, %1, off sc0"
                   :: "v"(fl + mem), "v"((u32)(t + 1)) : "memory");
  }
}

// ================= FALLBACK path (round-1 proven kernels, IF-scope) =================

__global__ void k_cast(const float* __restrict__ x, const float* __restrict__ whh,
                       const float* __restrict__ wih, const float* __restrict__ h0,
                       bf16* __restrict__ xb, bf16* __restrict__ whhb,
                       bf16* __restrict__ wihb, bf16* __restrict__ rb,
                       u32* __restrict__ bar)
{
  long i = (long)blockIdx.x * 256 + threadIdx.x;
  if (i < 8388608L) {
    xb[i] = __float2bfloat16(x[i]);
  } else if (i < 8388608L + 4194304L) {
    long j = i - 8388608L; whhb[j] = __float2bfloat16(whh[j]);
  } else if (i < 8388608L + 4194304L + 1048576L) {
    long j = i - 8388608L - 4194304L; wihb[j] = __float2bfloat16(wih[j]);
  } else if (i < 8388608L + 4194304L + 1048576L + 65536L) {
    long j = i - 8388608L - 4194304L - 1048576L;
    int b = (int)(j >> 10), h = (int)(j & 1023);
    rb[((long)b * TP1) * Hn + h] = __float2bfloat16(h0[j]);
  }
  if (blockIdx.x == 0 && threadIdx.x < 256) bar[threadIdx.x] = 0u;
}

__global__ void __launch_bounds__(256, 1)
k_lstm_if(const bf16* __restrict__ xb, const bf16* __restrict__ whhb,
          const bf16* __restrict__ wihb, const float* __restrict__ bih,
          const float* __restrict__ bhh, const float* __restrict__ c0,
          bf16* __restrict__ rb, float* __restrict__ outH, float* __restrict__ outC,
          u32* flags)
{
  const int tid = threadIdx.x;
  const int w = tid >> 6, l = tid & 63;
  const int lo16 = l & 15, q = l >> 4;
  const int g = blockIdx.x >> 6;
  const int mem = blockIdx.x & 63;
  const int bG0 = g << 4;

  short8 wf[4][10];
  {
    const int wrow = (mem << 4) + lo16;
#pragma unroll
    for (int j = 0; j < 4; ++j) {
#pragma unroll
      for (int kk = 0; kk < 10; ++kk) {
        const int kb = w * 10 + kk;
        if (kb < 32)
          wf[j][kk] = ld8(whhb + (long)(j * Hn + wrow) * Hn + kb * 32 + q * 8);
        else
          wf[j][kk] = ld8(wihb + (long)(j * Hn + wrow) * In + (kb - 32) * 32 + q * 8);
      }
    }
  }

  const int bl = tid & 15, diml = tid >> 4;
  const int bb = bG0 + bl;
  const int dloc = (mem << 4) + diml;
  const float bi0 = bih[dloc]          + bhh[dloc];
  const float bi1 = bih[Hn + dloc]     + bhh[Hn + dloc];
  const float bi2 = bih[2 * Hn + dloc] + bhh[2 * Hn + dloc];
  const float bi3 = bih[3 * Hn + dloc] + bhh[3 * Hn + dloc];
  float cst = c0[(long)bb * Hn + dloc];

  const int sb = tid >> 4, tl = tid & 15;

  __shared__ __align__(16) unsigned char Atile[16 * 2576];
  __shared__ float zbuf[4][4][16][17];

  u32* fl = flags + g * 64;

  const u64* xrow = (const u64*)(xb + (long)(bG0 + sb) * Tn * In);
  const u64* rrow = (const u64*)(rb + (long)(bG0 + sb) * TP1 * Hn);
  u64* ldsr = (u64*)(Atile + sb * 2576);
  u64* ldsx = (u64*)(Atile + sb * 2576 + 2048);

  for (int t = 0; t < Tn; ++t) {
    u64 xv[4];
    {
      const u64* xp = xrow + (long)t * (In / 4);
#pragma unroll
      for (int jx = 0; jx < 4; ++jx) xv[jx] = xp[tl + 16 * jx];
    }

    if (t > 0) {
      if (w == 0) {
        const u32 tgt = (u32)t;
        while (true) {
          u32 f = __hip_atomic_load(&fl[l], __ATOMIC_RELAXED, __HIP_MEMORY_SCOPE_AGENT);
          if (__ballot(f < tgt) == 0ULL) break;
        }
        __asm__ __volatile__("" ::: "memory");
      }
      __syncthreads();
    }

    u64 rv[16];
    {
      const u64* rp = rrow + (long)t * (Hn / 4);
#pragma unroll
      for (int j = 0; j < 16; ++j)
        rv[j] = __hip_atomic_load(rp + tl + 16 * j, __ATOMIC_RELAXED, __HIP_MEMORY_SCOPE_AGENT);
    }
#pragma unroll
    for (int jx = 0; jx < 4; ++jx) ldsx[tl + 16 * jx] = xv[jx];
#pragma unroll
    for (int j = 0; j < 16; ++j) ldsr[tl + 16 * j] = rv[j];
    __syncthreads();

    f32x4 a0 = {0,0,0,0}, a1 = {0,0,0,0}, a2 = {0,0,0,0}, a3 = {0,0,0,0};
    short8 af[10];
#pragma unroll
    for (int kk = 0; kk < 10; ++kk)
      af[kk] = *(const short8*)(Atile + lo16 * 2576 + ((w * 10 + kk) * 32 + q * 8) * 2);
#pragma unroll
    for (int kk = 0; kk < 10; ++kk) {
      a0 = __builtin_amdgcn_mfma_f32_16x16x32_bf16(af[kk], wf[0][kk], a0, 0, 0, 0);
      a1 = __builtin_amdgcn_mfma_f32_16x16x32_bf16(af[kk], wf[1][kk], a1, 0, 0, 0);
      a2 = __builtin_amdgcn_mfma_f32_16x16x32_bf16(af[kk], wf[2][kk], a2, 0, 0, 0);
      a3 = __builtin_amdgcn_mfma_f32_16x16x32_bf16(af[kk], wf[3][kk], a3, 0, 0, 0);
    }
#pragma unroll
    for (int r = 0; r < 4; ++r) {
      zbuf[w][0][lo16][q * 4 + r] = a0[r];
      zbuf[w][1][lo16][q * 4 + r] = a1[r];
      zbuf[w][2][lo16][q * 4 + r] = a2[r];
      zbuf[w][3][lo16][q * 4 + r] = a3[r];
    }
    __syncthreads();

    float zi = zbuf[0][0][diml][bl] + zbuf[1][0][diml][bl] + zbuf[2][0][diml][bl] + zbuf[3][0][diml][bl] + bi0;
    float zf = zbuf[0][1][diml][bl] + zbuf[1][1][diml][bl] + zbuf[2][1][diml][bl] + zbuf[3][1][diml][bl] + bi1;
    float zg = zbuf[0][2][diml][bl] + zbuf[1][2][diml][bl] + zbuf[2][2][diml][bl] + zbuf[3][2][diml][bl] + bi2;
    float zo = zbuf[0][3][diml][bl] + zbuf[1][3][diml][bl] + zbuf[2][3][diml][bl] + zbuf[3][3][diml][bl] + bi3;
    float iv = sigm(zi), fv = sigm(zf), gv = ftanh(zg), ov = sigm(zo);
    cst = fv * cst + iv * gv;
    float hv = ov * ftanh(cst);

    float ph = __shfl_xor(hv, 16, 64);
    u16 mb = __builtin_bit_cast(u16, __float2bfloat16(hv));
    u16 pb = __builtin_bit_cast(u16, __float2bfloat16(ph));
    if ((diml & 1) == 0) {
      u32 pack = (u32)mb | ((u32)pb << 16);
      u32* dst = (u32*)(rb + ((long)bb * TP1 + t + 1) * Hn + dloc);
      __hip_atomic_store(dst, pack, __ATOMIC_RELAXED, __HIP_MEMORY_SCOPE_AGENT);
    }
    if (t == Tn - 1) {
      outH[(long)bb * Hn + dloc] = hv;
      outC[(long)bb * Hn + dloc] = cst;
    }

    __asm__ __volatile__("s_waitcnt vmcnt(0)" ::: "memory");
    __syncthreads();
    if (tid == 0 && t < Tn - 1)
      __hip_atomic_store(&fl[mem], (u32)(t + 1), __ATOMIC_RELAXED, __HIP_MEMORY_SCOPE_AGENT);
  }
}

// ================= host =================

extern "C" void kernel_launch(void* const* d_in, const int* in_sizes, int n_in,
                              void* d_out, int out_size, void* d_ws, size_t ws_size,
                              hipStream_t stream)
{
  (void)in_sizes; (void)n_in; (void)out_size;
  const float* x    = (const float*)d_in[0];
  const float* h0   = (const float*)d_in[2];
  const float* c0   = (const float*)d_in[3];
  const float* Wih  = (const float*)d_in[4];
  const float* Whh  = (const float*)d_in[5];
  const float* bih  = (const float*)d_in[6];
  const float* bhh  = (const float*)d_in[7];
  const float* Wsh  = (const float*)d_in[8];
  const float* bsh  = (const float*)d_in[9];
  const float* was  = (const float*)d_in[10];
  const float* bas  = (const float*)d_in[11];
  const float* war  = (const float*)d_in[12];
  const float* barr = (const float*)d_in[13];
  const float* Wst  = (const float*)d_in[14];
  const float* bst  = (const float*)d_in[15];
  const float* Wrw  = (const float*)d_in[16];
  const float* brw  = (const float*)d_in[17];

  char* ws = (char*)d_ws;
  size_t off = 0;
  auto alloc = [&](size_t bytes) -> void* {
    void* p = ws + off; off += (bytes + 255) & ~(size_t)255; return p;
  };
  bf16* whhb  = (bf16*)alloc((size_t)4 * Hn * Hn * 2);
  bf16* wihb  = (bf16*)alloc((size_t)4 * Hn * In * 2);
  bf16* rb    = (bf16*)alloc((size_t)Bn * TP1 * Hn * 2);
  bf16* Gb    = (bf16*)alloc((size_t)16 * Hn * 2);
  float* Gpart= (float*)alloc((size_t)8 * 16 * Hn * 4);
  float* cv   = (float*)alloc(16 * 4);
  float* P    = (float*)alloc((size_t)Bn * Tn * 16 * 4);
  u32*  barp  = (u32*)alloc(2048);

  float* outS = (float*)d_out;
  float* outR = outS + (size_t)Bn * Tn * Fn;
  float* outH = outR + (size_t)Bn * Tn;
  float* outC = outH + (size_t)Bn * Hn;

  const size_t XZ_BYTES = (size_t)Tn * Bn * Hn * 4 * 2;   // 256 MiB
  const bool big = (ws_size == 0) || (ws_size >= off + XZ_BYTES + 65536);

  k_fold_part<<<dim3(4, 16, 8), 256, 0, stream>>>(Wsh, Wst, Wrw, was, war, Gpart);
  k_g2b<<<64, 256, 0, stream>>>(Gpart, Gb);
  k_const<<<1, 64, 0, stream>>>(bsh, Wst, bst, Wrw, brw, was, bas, war, barr, cv);

  if (big) {
    bf16* xz = (bf16*)alloc(XZ_BYTES);
    const long NC = 4194304L + 1048576L + 65536L;
    k_castw<<<dim3((unsigned)(NC / 256)), 256, 0, stream>>>(Whh, Wih, h0, whhb, wihb, rb, barp);
    k_xz<<<dim3(16, 2048), 256, 0, stream>>>(x, wihb, xz);
    k_lstm_x<<<256, 512, 0, stream>>>(whhb, bih, bhh, c0, xz, rb, outH, outC, barp);
  } else {
    bf16* xb = (bf16*)alloc((size_t)Bn * Tn * In * 2);
    const long NCAST = 8388608L + 4194304L + 1048576L + 65536L;
    k_cast<<<dim3((unsigned)(NCAST / 256)), 256, 0, stream>>>(x, Whh, Wih, h0, xb, whhb, wihb, rb, barp);
    void* args[] = { (void*)&xb, (void*)&whhb, (void*)&wihb, (void*)&bih, (void*)&bhh,
                     (void*)&c0, (void*)&rb, (void*)&outH, (void*)&outC, (void*)&barp };
    hipError_t e = hipLaunchCooperativeKernel((const void*)k_lstm_if, dim3(256), dim3(256),
                                              args, 0, stream);
    if (e != hipSuccess) {
      k_lstm_if<<<256, 256, 0, stream>>>(xb, whhb, wihb, bih, bhh, c0, rb, outH, outC, barp);
    }
  }

  k_proj<<<512, 256, 0, stream>>>(rb, Gb, cv, P);
  k_scan<<<64, 64, 0, stream>>>(P, outS, outR);
}

// Round 4
// 1746.987 us; speedup vs baseline: 1.7707x; 1.5918x over previous
//
#include <hip/hip_runtime.h>
#include <hip/hip_bf16.h>
#include <math.h>

// Problem constants
#define Bn 64
#define Tn 512
#define In 256
#define Hn 1024
#define Fn 11
#define TP1 513       // T+1 slots in r history (slot 0 = h0)

typedef __attribute__((ext_vector_type(8))) short short8;  // 8 bf16 (4 VGPRs)
typedef __attribute__((ext_vector_type(4))) float f32x4;
typedef unsigned short u16;
typedef unsigned int u32;
typedef unsigned long long u64;
typedef __hip_bfloat16 bf16;

__device__ __forceinline__ float sigm(float x) { return 1.0f / (1.0f + __expf(-x)); }
// fast tanh via hardware exp; clamped so e never overflows (tanh(+-15) == +-1 in f32)
__device__ __forceinline__ float ftanh(float x) {
  float xc = fminf(fmaxf(x, -15.0f), 15.0f);
  float e = __expf(2.0f * xc);
  return (e - 1.0f) / (e + 1.0f);
}
__device__ __forceinline__ short8 ld8(const bf16* p) { return *(const short8*)p; }

// ---------------- cast inputs to bf16, zero barrier flags / counters / table ----------------
// bar layout (u32): [0..255] group step-flags; [256] arrive counter;
// [264..519] per-block XCD table; rest spare. Zero [0..1023] every epoch.
__global__ void k_cast(const float* __restrict__ x, const float* __restrict__ whh,
                       const float* __restrict__ wih, const float* __restrict__ h0,
                       bf16* __restrict__ xb, bf16* __restrict__ whhb,
                       bf16* __restrict__ wihb, bf16* __restrict__ rb,
                       u32* __restrict__ bar)
{
  long i = (long)blockIdx.x * 256 + threadIdx.x;
  if (i < 8388608L) {                                   // x: B*T*I
    xb[i] = __float2bfloat16(x[i]);
  } else if (i < 8388608L + 4194304L) {                 // W_hh: 4H*H
    long j = i - 8388608L; whhb[j] = __float2bfloat16(whh[j]);
  } else if (i < 8388608L + 4194304L + 1048576L) {      // W_ih: 4H*I
    long j = i - 8388608L - 4194304L; wihb[j] = __float2bfloat16(wih[j]);
  } else if (i < 8388608L + 4194304L + 1048576L + 65536L) {  // h0 -> r slot 0
    long j = i - 8388608L - 4194304L - 1048576L;
    int b = (int)(j >> 10), h = (int)(j & 1023);
    rb[((long)b * TP1) * Hn + h] = __float2bfloat16(h0[j]);
  }
  if (blockIdx.x < 4 && threadIdx.x < 256)
    bar[blockIdx.x * 256 + threadIdx.x] = 0u;
}

// ---------------- fold post-LSTM linears: G[16][H] = V @ W_sh ----------------
__global__ void k_fold_part(const float* __restrict__ Wsh, const float* __restrict__ Wst,
                            const float* __restrict__ Wrw, const float* __restrict__ was,
                            const float* __restrict__ war, float* __restrict__ Gpart)
{
  int k = blockIdx.x * 256 + threadIdx.x;   // grid.x = 4 -> k in [0,1024)
  int j = blockIdx.y;                       // 16
  int h0 = blockIdx.z * 128;                // grid.z = 8
  const float* V = nullptr;
  if (j < 11) V = Wst + j * Hn;
  else if (j == 11) V = Wrw;
  else if (j == 12) V = was;
  else if (j == 13) V = war;
  float acc = 0.f;
  if (V) {
    for (int h = h0; h < h0 + 128; ++h) acc += V[h] * Wsh[(long)h * Hn + k];
  }
  Gpart[((long)blockIdx.z * 16 + j) * Hn + k] = acc;
}

__global__ void k_g2b(const float* __restrict__ Gpart, bf16* __restrict__ Gb)
{
  int i = blockIdx.x * 256 + threadIdx.x;   // 16384
  float s = 0.f;
  for (int z = 0; z < 8; ++z) s += Gpart[(long)z * 16384 + i];
  Gb[i] = __float2bfloat16(s);
}

__global__ void k_const(const float* __restrict__ bsh, const float* __restrict__ Wst,
                        const float* __restrict__ bst, const float* __restrict__ Wrw,
                        const float* __restrict__ brw, const float* __restrict__ was,
                        const float* __restrict__ bas, const float* __restrict__ war,
                        const float* __restrict__ bar_, float* __restrict__ cv)
{
  int j = threadIdx.x;
  if (j >= 16) return;
  const float* V = nullptr; float bb = 0.f;
  if (j < 11) { V = Wst + j * Hn; bb = bst[j]; }
  else if (j == 11) { V = Wrw; bb = brw[0]; }
  else if (j == 12) { V = was; bb = bas[0]; }
  else if (j == 13) { V = war; bb = bar_[0]; }
  float acc = 0.f;
  if (V) for (int h = 0; h < Hn; ++h) acc += bsh[h] * V[h];
  cv[j] = acc + bb;
}

// ================= fast path: verified XCD-local LSTM, hang-proof =================
// 8 groups x 32 WGs x 512 thr. Group/rank derived from the REAL HW_REG_XCC_ID via a
// published table + epoch arrive-barrier; verified (exactly 32 WGs per XCD) before
// use. mode1: data (r loads / h stores) sc0-only -> served by the XCD's own L2;
// mode0 (verification failed): blockIdx grouping + full agent scope (R1 semantics).
// Step-flags are ALWAYS agent-scope (sc0 sc1, IF) -> flag visibility guaranteed in
// both modes; no flag-based hang is possible.
__global__ void __launch_bounds__(512, 2)
k_lstm_x(const bf16* __restrict__ xb, const bf16* __restrict__ whhb,
         const bf16* __restrict__ wihb, const float* __restrict__ bih,
         const float* __restrict__ bhh, const float* __restrict__ c0,
         bf16* __restrict__ rb, float* __restrict__ outH, float* __restrict__ outC,
         u32* flags)
{
  const int tid = threadIdx.x;
  const int w = tid >> 6, l = tid & 63;
  const int lo16 = l & 15, q = l >> 4;
  const int kq = w & 1, nh = w >> 1;

  __shared__ int s_g, s_mem, s_mode;
  // A-tile: 16 rows x 1280 bf16 (2560B) + 16B pad = 2576B/row. Rows 0..7 = batches
  // (r in bytes [0,2048), x in [2048,2560)); rows 8..15 stay zero (MFMA m-pad).
  __shared__ __align__(16) unsigned char Atile[16 * 2576];
  __shared__ float zbuf[2][8][16][9];   // [K-half][ntile][n(dim16)][m(batch)+pad]

  // ---- group/rank discovery: publish XCC, epoch arrive-barrier, verify ----
  if (w == 0) {
    u32 xcc;
    asm volatile("s_getreg_b32 %0, hwreg(HW_REG_XCC_ID)" : "=s"(xcc));
    xcc &= 7u;
    if (l == 0) {
      __hip_atomic_store(&flags[264 + blockIdx.x], xcc, __ATOMIC_RELAXED,
                         __HIP_MEMORY_SCOPE_AGENT);
      u32 old = __hip_atomic_fetch_add(&flags[256], 1u, __ATOMIC_RELEASE,
                                       __HIP_MEMORY_SCOPE_AGENT);
      u32 tg = (old / 256u + 1u) * 256u;   // epoch-aware: robust to replay
      while (__hip_atomic_load(&flags[256], __ATOMIC_ACQUIRE,
                               __HIP_MEMORY_SCOPE_AGENT) < tg) {}
    }
    __asm__ __volatile__("" ::: "memory");
    // wave-parallel scan of the 256-entry table
    u64 clo = 0, chi = 0; int pmem = 0;
#pragma unroll
    for (int k = 0; k < 4; ++k) {
      const int idx = l * 4 + k;
      u32 v = __hip_atomic_load(&flags[264 + idx], __ATOMIC_RELAXED,
                                __HIP_MEMORY_SCOPE_AGENT) & 7u;
      if (v < 4u) clo += 1ULL << (16u * v);
      else        chi += 1ULL << (16u * (v - 4u));
      pmem += (idx < (int)blockIdx.x && v == xcc) ? 1 : 0;
    }
#pragma unroll
    for (int off = 1; off < 64; off <<= 1) {
      clo  += __shfl_xor((unsigned long long)clo, off, 64);
      chi  += __shfl_xor((unsigned long long)chi, off, 64);
      pmem += __shfl_xor(pmem, off, 64);
    }
    bool ok = true;
#pragma unroll
    for (int xx = 0; xx < 4; ++xx) {
      ok = ok && (((clo >> (16 * xx)) & 0xFFFFULL) == 32ULL);
      ok = ok && (((chi >> (16 * xx)) & 0xFFFFULL) == 32ULL);
    }
    if (l == 0) {
      s_mode = ok ? 1 : 0;
      s_g    = ok ? (int)xcc : (int)(blockIdx.x & 7);
      s_mem  = ok ? pmem     : (int)(blockIdx.x >> 3);
    }
  }
  // zero A-tile rows 8..15 once (MFMA m-rows 8..15 must stay 0)
  {
    u64* za = (u64*)(Atile + 8 * 2576);
    for (int i = tid; i < (8 * 2576) / 8; i += 512) za[i] = 0;
  }
  __syncthreads();
  const int g = s_g, mem = s_mem;
  const bool xloc = (s_mode != 0);
  const int bG0 = g << 3;                    // 8 batches per group

  // weight fragments: 2 ntiles x 20 kb = 40 short8 = 160 VGPR
  short8 wf[2][20];
#pragma unroll
  for (int nt = 0; nt < 2; ++nt) {
    const int ntg = nh * 2 + nt;
    const int j = ntg >> 1;                  // gate
    const long zrow = (long)(j * Hn + (mem << 5) + ((ntg & 1) << 4) + lo16);
#pragma unroll
    for (int kk = 0; kk < 20; ++kk) {
      const int kb = kq * 20 + kk;
      if (kb < 32) wf[nt][kk] = ld8(whhb + zrow * Hn + kb * 32 + q * 8);
      else         wf[nt][kk] = ld8(wihb + zrow * In + (kb - 32) * 32 + q * 8);
    }
  }

  // gate-phase mapping (tid < 256): batch bl (0..7), local dim dl (0..31)
  const int bl = tid & 7, dl = tid >> 3;
  const int bb = bG0 + bl;
  const int dloc = (mem << 5) + (dl & 31);
  float bi0 = 0, bi1 = 0, bi2 = 0, bi3 = 0, cst = 0;
  if (tid < 256) {
    bi0 = bih[dloc]          + bhh[dloc];
    bi1 = bih[Hn + dloc]     + bhh[Hn + dloc];
    bi2 = bih[2 * Hn + dloc] + bhh[2 * Hn + dloc];
    bi3 = bih[3 * Hn + dloc] + bhh[3 * Hn + dloc];
    cst = c0[(long)bb * Hn + dloc];
  }

  u32* fl = flags + g * 32;                  // 32 flags = one 128B line per group
  const u64* rbase = (const u64*)(rb + ((long)(bG0 + w) * TP1) * Hn) + l;   // wave's batch
  const u64* xq    = (const u64*)(xb + (long)(bG0 + w) * Tn * In) + l;      // 64 u64 / row
  u32* hbase = (u32*)(rb + ((long)bb * TP1 + 1) * Hn + dloc);

  for (int t = 0; t < Tn; ++t) {
    // x prefetch: read-only, normal cached load; hides under the poll
    u64 xv = xq[(long)t * 64];

    // wait for step t-1: wave 0 polls the group's 32 flags (agent scope, proven)
    if (t > 0) {
      if (w == 0) {
        const u32 tgt = (u32)t;
        while (true) {
          u32 f = __hip_atomic_load(&fl[l & 31], __ATOMIC_RELAXED,
                                    __HIP_MEMORY_SCOPE_AGENT);
          if (__ballot(f < tgt) == 0ULL) break;
        }
        __asm__ __volatile__("" ::: "memory");
      }
      __syncthreads();
    }

    // r staging: wave w loads its batch's slot t.
    // mode1: sc0 (L1-bypass, served by this XCD's L2 -- producers are same-XCD)
    // mode0: sc0 sc1 (IF, producers may be cross-XCD)
    u64 rv0, rv1, rv2, rv3;
    {
      const u64* rp = rbase + (long)t * 256;
      if (xloc) {
        asm volatile(
          "global_load_dwordx2 %0, %4, off sc0\n\t"
          "global_load_dwordx2 %1, %4, off offset:512 sc0\n\t"
          "global_load_dwordx2 %2, %4, off offset:1024 sc0\n\t"
          "global_load_dwordx2 %3, %4, off offset:1536 sc0\n\t"
          "s_waitcnt vmcnt(0)"
          : "=&v"(rv0), "=&v"(rv1), "=&v"(rv2), "=&v"(rv3)
          : "v"(rp) : "memory");
      } else {
        asm volatile(
          "global_load_dwordx2 %0, %4, off sc0 sc1\n\t"
          "global_load_dwordx2 %1, %4, off offset:512 sc0 sc1\n\t"
          "global_load_dwordx2 %2, %4, off offset:1024 sc0 sc1\n\t"
          "global_load_dwordx2 %3, %4, off offset:1536 sc0 sc1\n\t"
          "s_waitcnt vmcnt(0)"
          : "=&v"(rv0), "=&v"(rv1), "=&v"(rv2), "=&v"(rv3)
          : "v"(rp) : "memory");
      }
    }
    {
      u64* lr = (u64*)(Atile + w * 2576) + l;
      lr[0] = rv0; lr[64] = rv1; lr[128] = rv2; lr[192] = rv3;
      ((u64*)(Atile + w * 2576 + 2048))[l] = xv;
    }
    __syncthreads();

    // MFMA: wave's K-half (20 kb) x 2 ntiles; A-frags prefetched in groups of 4
    f32x4 a0 = {0,0,0,0}, a1 = {0,0,0,0};
    {
      const unsigned char* arow = Atile + lo16 * 2576 + kq * 1280 + q * 16;
#pragma unroll
      for (int gq = 0; gq < 5; ++gq) {
        short8 af0 = *(const short8*)(arow + (gq * 4 + 0) * 64);
        short8 af1 = *(const short8*)(arow + (gq * 4 + 1) * 64);
        short8 af2 = *(const short8*)(arow + (gq * 4 + 2) * 64);
        short8 af3 = *(const short8*)(arow + (gq * 4 + 3) * 64);
        a0 = __builtin_amdgcn_mfma_f32_16x16x32_bf16(af0, wf[0][gq * 4 + 0], a0, 0, 0, 0);
        a1 = __builtin_amdgcn_mfma_f32_16x16x32_bf16(af0, wf[1][gq * 4 + 0], a1, 0, 0, 0);
        a0 = __builtin_amdgcn_mfma_f32_16x16x32_bf16(af1, wf[0][gq * 4 + 1], a0, 0, 0, 0);
        a1 = __builtin_amdgcn_mfma_f32_16x16x32_bf16(af1, wf[1][gq * 4 + 1], a1, 0, 0, 0);
        a0 = __builtin_amdgcn_mfma_f32_16x16x32_bf16(af2, wf[0][gq * 4 + 2], a0, 0, 0, 0);
        a1 = __builtin_amdgcn_mfma_f32_16x16x32_bf16(af2, wf[1][gq * 4 + 2], a1, 0, 0, 0);
        a0 = __builtin_amdgcn_mfma_f32_16x16x32_bf16(af3, wf[0][gq * 4 + 3], a0, 0, 0, 0);
        a1 = __builtin_amdgcn_mfma_f32_16x16x32_bf16(af3, wf[1][gq * 4 + 3], a1, 0, 0, 0);
      }
    }
    // D layout: m(batch) = q*4+r (only m<8 real), n(dim16) = lo16
    if (q < 2) {
      const int ntg0 = nh * 2;
#pragma unroll
      for (int r = 0; r < 4; ++r) {
        zbuf[kq][ntg0][lo16][q * 4 + r]     = a0[r];
        zbuf[kq][ntg0 + 1][lo16][q * 4 + r] = a1[r];
      }
    }
    __syncthreads();

    if (tid < 256) {
      const int n16 = dl & 15, hi = dl >> 4;
      float z0 = zbuf[0][0 + hi][n16][bl] + zbuf[1][0 + hi][n16][bl] + bi0;
      float z1 = zbuf[0][2 + hi][n16][bl] + zbuf[1][2 + hi][n16][bl] + bi1;
      float z2 = zbuf[0][4 + hi][n16][bl] + zbuf[1][4 + hi][n16][bl] + bi2;
      float z3 = zbuf[0][6 + hi][n16][bl] + zbuf[1][6 + hi][n16][bl] + bi3;
      float iv = sigm(z0), fv = sigm(z1), gv = ftanh(z2), ov = sigm(z3);
      cst = fv * cst + iv * gv;
      float hv = ov * ftanh(cst);

      float ph = __shfl_xor(hv, 8, 64);       // partner holds dl^1
      if ((dl & 1) == 0) {
        u16 mb = __builtin_bit_cast(u16, __float2bfloat16(hv));
        u16 pb = __builtin_bit_cast(u16, __float2bfloat16(ph));
        u32 pack = (u32)mb | ((u32)pb << 16);
        u32* dst = hbase + (long)t * 512;
        if (xloc)
          asm volatile("global_store_dword %0, %1, off sc0" :: "v"(dst), "v"(pack) : "memory");
        else
          asm volatile("global_store_dword %0, %1, off sc0 sc1" :: "v"(dst), "v"(pack) : "memory");
      }
      if (t == Tn - 1) {
        outH[(long)bb * Hn + dloc] = hv;
        outC[(long)bb * Hn + dloc] = cst;
      }
    }
    // drain h stores to their coherence point, then block barrier, then signal
    asm volatile("s_waitcnt vmcnt(0)" ::: "memory");
    __syncthreads();
    if (tid == 0 && t < Tn - 1)
      __hip_atomic_store(&fl[mem], (u32)(t + 1), __ATOMIC_RELAXED,
                         __HIP_MEMORY_SCOPE_AGENT);
  }
}

// ================= FALLBACK (round-1 proven IF-scope kernel) =================

__global__ void __launch_bounds__(256, 1)
k_lstm_if(const bf16* __restrict__ xb, const bf16* __restrict__ whhb,
          const bf16* __restrict__ wihb, const float* __restrict__ bih,
          const float* __restrict__ bhh, const float* __restrict__ c0,
          bf16* __restrict__ rb, float* __restrict__ outH, float* __restrict__ outC,
          u32* flags)
{
  const int tid = threadIdx.x;
  const int w = tid >> 6, l = tid & 63;
  const int lo16 = l & 15, q = l >> 4;
  const int g = blockIdx.x >> 6;
  const int mem = blockIdx.x & 63;
  const int bG0 = g << 4;

  short8 wf[4][10];
  {
    const int wrow = (mem << 4) + lo16;
#pragma unroll
    for (int j = 0; j < 4; ++j) {
#pragma unroll
      for (int kk = 0; kk < 10; ++kk) {
        const int kb = w * 10 + kk;
        if (kb < 32)
          wf[j][kk] = ld8(whhb + (long)(j * Hn + wrow) * Hn + kb * 32 + q * 8);
        else
          wf[j][kk] = ld8(wihb + (long)(j * Hn + wrow) * In + (kb - 32) * 32 + q * 8);
      }
    }
  }

  const int bl = tid & 15, diml = tid >> 4;
  const int bb = bG0 + bl;
  const int dloc = (mem << 4) + diml;
  const float bi0 = bih[dloc]          + bhh[dloc];
  const float bi1 = bih[Hn + dloc]     + bhh[Hn + dloc];
  const float bi2 = bih[2 * Hn + dloc] + bhh[2 * Hn + dloc];
  const float bi3 = bih[3 * Hn + dloc] + bhh[3 * Hn + dloc];
  float cst = c0[(long)bb * Hn + dloc];

  const int sb = tid >> 4, tl = tid & 15;

  __shared__ __align__(16) unsigned char Atile[16 * 2576];
  __shared__ float zbuf[4][4][16][17];

  u32* fl = flags + g * 64;

  const u64* xrow = (const u64*)(xb + (long)(bG0 + sb) * Tn * In);
  const u64* rrow = (const u64*)(rb + (long)(bG0 + sb) * TP1 * Hn);
  u64* ldsr = (u64*)(Atile + sb * 2576);
  u64* ldsx = (u64*)(Atile + sb * 2576 + 2048);

  for (int t = 0; t < Tn; ++t) {
    u64 xv[4];
    {
      const u64* xp = xrow + (long)t * (In / 4);
#pragma unroll
      for (int jx = 0; jx < 4; ++jx) xv[jx] = xp[tl + 16 * jx];
    }

    if (t > 0) {
      if (w == 0) {
        const u32 tgt = (u32)t;
        while (true) {
          u32 f = __hip_atomic_load(&fl[l], __ATOMIC_RELAXED, __HIP_MEMORY_SCOPE_AGENT);
          if (__ballot(f < tgt) == 0ULL) break;
        }
        __asm__ __volatile__("" ::: "memory");
      }
      __syncthreads();
    }

    u64 rv[16];
    {
      const u64* rp = rrow + (long)t * (Hn / 4);
#pragma unroll
      for (int j = 0; j < 16; ++j)
        rv[j] = __hip_atomic_load(rp + tl + 16 * j, __ATOMIC_RELAXED, __HIP_MEMORY_SCOPE_AGENT);
    }
#pragma unroll
    for (int jx = 0; jx < 4; ++jx) ldsx[tl + 16 * jx] = xv[jx];
#pragma unroll
    for (int j = 0; j < 16; ++j) ldsr[tl + 16 * j] = rv[j];
    __syncthreads();

    f32x4 a0 = {0,0,0,0}, a1 = {0,0,0,0}, a2 = {0,0,0,0}, a3 = {0,0,0,0};
    short8 af[10];
#pragma unroll
    for (int kk = 0; kk < 10; ++kk)
      af[kk] = *(const short8*)(Atile + lo16 * 2576 + ((w * 10 + kk) * 32 + q * 8) * 2);
#pragma unroll
    for (int kk = 0; kk < 10; ++kk) {
      a0 = __builtin_amdgcn_mfma_f32_16x16x32_bf16(af[kk], wf[0][kk], a0, 0, 0, 0);
      a1 = __builtin_amdgcn_mfma_f32_16x16x32_bf16(af[kk], wf[1][kk], a1, 0, 0, 0);
      a2 = __builtin_amdgcn_mfma_f32_16x16x32_bf16(af[kk], wf[2][kk], a2, 0, 0, 0);
      a3 = __builtin_amdgcn_mfma_f32_16x16x32_bf16(af[kk], wf[3][kk], a3, 0, 0, 0);
    }
#pragma unroll
    for (int r = 0; r < 4; ++r) {
      zbuf[w][0][lo16][q * 4 + r] = a0[r];
      zbuf[w][1][lo16][q * 4 + r] = a1[r];
      zbuf[w][2][lo16][q * 4 + r] = a2[r];
      zbuf[w][3][lo16][q * 4 + r] = a3[r];
    }
    __syncthreads();

    float zi = zbuf[0][0][diml][bl] + zbuf[1][0][diml][bl] + zbuf[2][0][diml][bl] + zbuf[3][0][diml][bl] + bi0;
    float zf = zbuf[0][1][diml][bl] + zbuf[1][1][diml][bl] + zbuf[2][1][diml][bl] + zbuf[3][1][diml][bl] + bi1;
    float zg = zbuf[0][2][diml][bl] + zbuf[1][2][diml][bl] + zbuf[2][2][diml][bl] + zbuf[3][2][diml][bl] + bi2;
    float zo = zbuf[0][3][diml][bl] + zbuf[1][3][diml][bl] + zbuf[2][3][diml][bl] + zbuf[3][3][diml][bl] + bi3;
    float iv = sigm(zi), fv = sigm(zf), gv = ftanh(zg), ov = sigm(zo);
    cst = fv * cst + iv * gv;
    float hv = ov * ftanh(cst);

    float ph = __shfl_xor(hv, 16, 64);
    u16 mb = __builtin_bit_cast(u16, __float2bfloat16(hv));
    u16 pb = __builtin_bit_cast(u16, __float2bfloat16(ph));
    if ((diml & 1) == 0) {
      u32 pack = (u32)mb | ((u32)pb << 16);
      u32* dst = (u32*)(rb + ((long)bb * TP1 + t + 1) * Hn + dloc);
      __hip_atomic_store(dst, pack, __ATOMIC_RELAXED, __HIP_MEMORY_SCOPE_AGENT);
    }
    if (t == Tn - 1) {
      outH[(long)bb * Hn + dloc] = hv;
      outC[(long)bb * Hn + dloc] = cst;
    }

    __asm__ __volatile__("s_waitcnt vmcnt(0)" ::: "memory");
    __syncthreads();
    if (tid == 0 && t < Tn - 1)
      __hip_atomic_store(&fl[mem], (u32)(t + 1), __ATOMIC_RELAXED, __HIP_MEMORY_SCOPE_AGENT);
  }
}

// ---------------- project r onto folded 16-dim basis: P[B*T][16] ----------------
__global__ void k_proj(const bf16* __restrict__ rb, const bf16* __restrict__ Gb,
                       const float* __restrict__ cv, float* __restrict__ P)
{
  const int tid = threadIdx.x;
  const int w = tid >> 6, l = tid & 63;
  const int lo16 = l & 15, q = l >> 4;
  const int row = blockIdx.x * 64 + w * 16 + lo16;    // (b,t) flat
  const int b = row >> 9, t = row & 511;
  const bf16* ap = rb + ((long)b * TP1 + t + 1) * Hn + q * 8;
  const bf16* gp = Gb + (long)lo16 * Hn + q * 8;
  f32x4 a0 = {0,0,0,0}, a1 = {0,0,0,0};
#pragma unroll
  for (int kb = 0; kb < 32; kb += 2) {
    a0 = __builtin_amdgcn_mfma_f32_16x16x32_bf16(ld8(ap + kb * 32),      ld8(gp + kb * 32),      a0, 0, 0, 0);
    a1 = __builtin_amdgcn_mfma_f32_16x16x32_bf16(ld8(ap + kb * 32 + 32), ld8(gp + kb * 32 + 32), a1, 0, 0, 0);
  }
  f32x4 z = a0 + a1;
  float c = cv[lo16];
  const int rowbase = blockIdx.x * 64 + w * 16;
#pragma unroll
  for (int r = 0; r < 4; ++r)
    P[(long)(rowbase + q * 4 + r) * 16 + lo16] = z[r] + c;
}

// ---------------- per-batch online-softmax prefix scan ----------------
__global__ void k_scan(const float* __restrict__ P, float* __restrict__ outS,
                       float* __restrict__ outR)
{
  __shared__ float sp[Tn * 16];
  const int b = blockIdx.x, tid = threadIdx.x;
  for (int i = tid; i < Tn * 16; i += 64) sp[i] = P[(long)b * Tn * 16 + i];
  __syncthreads();
  const int j = tid;
  if (j < 12) {
    const bool isR = (j == 11);
    float m = -INFINITY, den = 0.f, num = 0.f;
    for (int t = 0; t < Tn; ++t) {
      float val = sp[t * 16 + j];
      float ll = sp[t * 16 + (isR ? 13 : 12)];
      float mn = fmaxf(m, ll);
      float al = __expf(m - mn);
      float e  = __expf(ll - mn);
      den = den * al + e;
      num = num * al + e * val;
      m = mn;
      float o = num / den;
      if (isR) outR[(long)b * Tn + t] = o;
      else     outS[(long)(b * Tn + t) * Fn + j] = o;
    }
  }
}

// ================= host =================

extern "C" void kernel_launch(void* const* d_in, const int* in_sizes, int n_in,
                              void* d_out, int out_size, void* d_ws, size_t ws_size,
                              hipStream_t stream)
{
  (void)in_sizes; (void)n_in; (void)out_size; (void)ws_size;
  const float* x    = (const float*)d_in[0];
  const float* h0   = (const float*)d_in[2];
  const float* c0   = (const float*)d_in[3];
  const float* Wih  = (const float*)d_in[4];
  const float* Whh  = (const float*)d_in[5];
  const float* bih  = (const float*)d_in[6];
  const float* bhh  = (const float*)d_in[7];
  const float* Wsh  = (const float*)d_in[8];
  const float* bsh  = (const float*)d_in[9];
  const float* was  = (const float*)d_in[10];
  const float* bas  = (const float*)d_in[11];
  const float* war  = (const float*)d_in[12];
  const float* barr = (const float*)d_in[13];
  const float* Wst  = (const float*)d_in[14];
  const float* bst  = (const float*)d_in[15];
  const float* Wrw  = (const float*)d_in[16];
  const float* brw  = (const float*)d_in[17];

  char* ws = (char*)d_ws;
  size_t off = 0;
  auto alloc = [&](size_t bytes) -> void* {
    void* p = ws + off; off += (bytes + 255) & ~(size_t)255; return p;
  };
  bf16* xb    = (bf16*)alloc((size_t)Bn * Tn * In * 2);
  bf16* whhb  = (bf16*)alloc((size_t)4 * Hn * Hn * 2);
  bf16* wihb  = (bf16*)alloc((size_t)4 * Hn * In * 2);
  bf16* rb    = (bf16*)alloc((size_t)Bn * TP1 * Hn * 2);
  bf16* Gb    = (bf16*)alloc((size_t)16 * Hn * 2);
  float* Gpart= (float*)alloc((size_t)8 * 16 * Hn * 4);
  float* cv   = (float*)alloc(16 * 4);
  float* P    = (float*)alloc((size_t)Bn * Tn * 16 * 4);
  u32*  barp  = (u32*)alloc(4096);

  float* outS = (float*)d_out;
  float* outR = outS + (size_t)Bn * Tn * Fn;
  float* outH = outR + (size_t)Bn * Tn;
  float* outC = outH + (size_t)Bn * Hn;

  const long NCAST = 8388608L + 4194304L + 1048576L + 65536L;
  k_cast<<<dim3((unsigned)(NCAST / 256)), 256, 0, stream>>>(x, Whh, Wih, h0, xb, whhb, wihb, rb, barp);
  k_fold_part<<<dim3(4, 16, 8), 256, 0, stream>>>(Wsh, Wst, Wrw, was, war, Gpart);
  k_g2b<<<64, 256, 0, stream>>>(Gpart, Gb);
  k_const<<<1, 64, 0, stream>>>(bsh, Wst, bst, Wrw, brw, was, bas, war, barr, cv);

  {
    void* args[] = { (void*)&xb, (void*)&whhb, (void*)&wihb, (void*)&bih, (void*)&bhh,
                     (void*)&c0, (void*)&rb, (void*)&outH, (void*)&outC, (void*)&barp };
    hipError_t e = hipLaunchCooperativeKernel((const void*)k_lstm_x, dim3(256), dim3(512),
                                              args, 0, stream);
    if (e != hipSuccess) {
      hipError_t e2 = hipLaunchCooperativeKernel((const void*)k_lstm_if, dim3(256), dim3(256),
                                                 args, 0, stream);
      if (e2 != hipSuccess)
        k_lstm_if<<<256, 256, 0, stream>>>(xb, whhb, wihb, bih, bhh, c0, rb, outH, outC, barp);
    }
  }

  k_proj<<<512, 256, 0, stream>>>(rb, Gb, cv, P);
  k_scan<<<64, 64, 0, stream>>>(P, outS, outR);
}